// Round 3
// baseline (91.897 us; speedup 1.0000x reference)
//
#include <hip/hip_runtime.h>

#define TS 1000

__device__ __forceinline__ double wred(double v) {
#pragma unroll
    for (int o = 32; o > 0; o >>= 1) v += __shfl_down(v, o, 64);
    return v;
}

__device__ __forceinline__ void scat(unsigned* bins, float v, unsigned val) {
    if (v != 0.0f) {
        int q = (int)(v * 1000.0f) - 1;
        if (q < 0) q += TS;
        atomicMax(&bins[q], val);
    }
}

__global__ void kinit(double* acc, int n) {
    int i = blockIdx.x * blockDim.x + threadIdx.x;
    if (i < n) acc[i] = 0.0;
}

// Even blocks: row transform (vy) + vt. Bins are WAVE-PRIVATE -> no block
// barriers at all; wave-level s_waitcnt lgkmcnt(0) orders scatter/readback.
// Next row's global loads are issued before processing the current row.
// Odd blocks: column transform (vx); stripe lives in registers (round-2),
// 4 scatter phases with block barriers (bins shared across waves).
__global__ __launch_bounds__(256, 5) void kmain(const float* __restrict__ R,
                                                const float* __restrict__ T,
                                                double* __restrict__ acc,
                                                int ncopy_mask) {
    __shared__ unsigned bins[8000];
    const int tid = threadIdx.x;
    const int lane = tid & 63, wv = tid >> 6;
    const int id = blockIdx.x;
    const uint4 z4 = make_uint4(0u, 0u, 0u, 0u);
    double* accrow = acc + (size_t)(id & ncopy_mask) * 16;

    double s0a = 0.0, s0b = 0.0, ssa = 0.0, ssb = 0.0;  // bin-MSE sums
    int c1 = 0;

    if ((id & 1) == 0) {
        // ================= rows: vt + vy (barrier-free) =================
        const int kid = id >> 1;  // 0..1023, 16 rows per block, 4 per wave
        unsigned* bR = bins + wv * 2000;
        unsigned* bT = bR + 1000;
        uint4* r4 = (uint4*)bR;
        uint4* t4 = (uint4*)bT;
        // wave-private clear: 500 uint4 covers this wave's R+T slices
        for (int g = lane; g < 500; g += 64) r4[g] = z4;

        const float4* R4 = (const float4*)(R + (size_t)(kid * 16 + wv * 4) * 512);
        const float4* T4 = (const float4*)(T + (size_t)(kid * 16 + wv * 4) * 512);
        double t0a = 0.0, t0b = 0.0, tsa = 0.0, tsb = 0.0;
        int tc1 = 0;

        float4 rv0 = R4[lane], rv1 = R4[lane + 64];
        float4 tv0 = T4[lane], tv1 = T4[lane + 64];
#pragma unroll
        for (int it = 0; it < 4; it++) {
            float4 nrv0, nrv1, ntv0, ntv1;
            if (it < 3) {  // prefetch next row (vmcnt, independent of lgkmcnt)
                const int o = (it + 1) * 128;
                nrv0 = R4[o + lane];
                nrv1 = R4[o + lane + 64];
                ntv0 = T4[o + lane];
                ntv1 = T4[o + lane + 64];
            }
            // own-wave clears / re-clears visible before scatter
            asm volatile("s_waitcnt lgkmcnt(0)" ::: "memory");
            float rr[8] = {rv0.x, rv0.y, rv0.z, rv0.w, rv1.x, rv1.y, rv1.z, rv1.w};
            float tt[8] = {tv0.x, tv0.y, tv0.z, tv0.w, tv1.x, tv1.y, tv1.z, tv1.w};
#pragma unroll
            for (int j = 0; j < 8; j++) {
                float a = rr[j], b = tt[j];
                float d = a - b, d2 = d * d;
                bool bz = (b == 0.0f);
                if (j & 1) {
                    tsb += (double)d2;
                    t0b += bz ? (double)d2 : 0.0;
                } else {
                    tsa += (double)d2;
                    t0a += bz ? (double)d2 : 0.0;
                }
                tc1 += bz ? 0 : 1;
                const unsigned w = (unsigned)((j < 4 ? lane : lane + 64) * 4 + (j & 3));
                scat(bR, a, w);
                scat(bT, b, w);
            }
            // own-wave scatters drained before readback
            asm volatile("s_waitcnt lgkmcnt(0)" ::: "memory");
            for (int g = lane; g < 250; g += 64) {
                uint4 rg = r4[g], tg = t4[g];
                unsigned any = rg.x | rg.y | rg.z | rg.w | tg.x | tg.y | tg.z | tg.w;
                if (any) {
                    if (it < 3) { r4[g] = z4; t4[g] = z4; }  // conditional re-clear
                    unsigned ru[4] = {rg.x, rg.y, rg.z, rg.w};
                    unsigned tu[4] = {tg.x, tg.y, tg.z, tg.w};
#pragma unroll
                    for (int j2 = 0; j2 < 4; j2++) {
                        float rb = (float)ru[j2], tb = (float)tu[j2];
                        float d = rb - tb, d2 = d * d;
                        bool tz = (tb == 0.0f);
                        if (j2 & 1) {
                            ssb += (double)d2;
                            s0b += tz ? (double)d2 : 0.0;
                        } else {
                            ssa += (double)d2;
                            s0a += tz ? (double)d2 : 0.0;
                        }
                        c1 += tz ? 0 : 1;
                    }
                }
            }
            if (it < 3) { rv0 = nrv0; rv1 = nrv1; tv0 = ntv0; tv1 = ntv1; }
        }
        double v0 = wred(t0a + t0b), v1 = wred(tsa + tsb), v2 = wred((double)tc1);
        double v3 = wred(s0a + s0b), v4 = wred(ssa + ssb), v5 = wred((double)c1);
        if (lane == 0) {
            atomicAdd(&accrow[0], v0);
            atomicAdd(&accrow[1], v1);
            atomicAdd(&accrow[2], v2);
            atomicAdd(&accrow[3], v3);
            atomicAdd(&accrow[4], v4);
            atomicAdd(&accrow[5], v5);
        }
    } else {
        // ================= columns: vx =================
        const int kid = id >> 1;    // 0..1023
        const int b = kid >> 5;     // image
        const int line = kid & 31;  // 16-column stripe
        const float* Rb = R + (size_t)b * (512 * 512) + (size_t)line * 16;
        const float* Tb = T + (size_t)b * (512 * 512) + (size_t)line * 16;

        // block-wide clear
        {
            uint4* p = (uint4*)bins;
            for (int i = tid; i < 2000; i += 256) p[i] = z4;
        }

        // Load whole stripe once: 4-lane group g=tid>>2 covers one row's 64B;
        // quad ownership rotates (sub=(tid+k)&3) so each phase has 2 matching
        // register quads per thread.
        float4 ra[8], ta[8];
#pragma unroll
        for (int k = 0; k < 8; k++) {
            const int h = k * 64 + (tid >> 2);
            const int sub = (tid + k) & 3;
            const size_t off = (size_t)h * 512 + sub * 4;
            ra[k] = *(const float4*)(Rb + off);
            ta[k] = *(const float4*)(Tb + off);
        }
        __syncthreads();  // clear visible to all waves

        uint4* r4 = (uint4*)bins;           // [4 cols][1000] for R
        uint4* t4 = (uint4*)(bins + 4000);  // [4 cols][1000] for T
#pragma unroll
        for (int p = 0; p < 4; p++) {
            if (p > 0) __syncthreads();  // re-clears visible to all waves
#pragma unroll
            for (int k = 0; k < 8; k++) {
                if (((tid + k) & 3) == p) {
                    const unsigned h = (unsigned)(k * 64 + (tid >> 2));
                    scat(bins + 0 * 1000, ra[k].x, h);
                    scat(bins + 1 * 1000, ra[k].y, h);
                    scat(bins + 2 * 1000, ra[k].z, h);
                    scat(bins + 3 * 1000, ra[k].w, h);
                    scat(bins + 4000 + 0 * 1000, ta[k].x, h);
                    scat(bins + 4000 + 1 * 1000, ta[k].y, h);
                    scat(bins + 4000 + 2 * 1000, ta[k].z, h);
                    scat(bins + 4000 + 3 * 1000, ta[k].w, h);
                }
            }
            __syncthreads();  // scatters visible to all waves
            for (int g = tid; g < 1000; g += 256) {
                uint4 rg = r4[g], tg = t4[g];
                unsigned any = rg.x | rg.y | rg.z | rg.w | tg.x | tg.y | tg.z | tg.w;
                if (any) {
                    if (p < 3) { r4[g] = z4; t4[g] = z4; }  // conditional re-clear
                    unsigned ru[4] = {rg.x, rg.y, rg.z, rg.w};
                    unsigned tu[4] = {tg.x, tg.y, tg.z, tg.w};
#pragma unroll
                    for (int j = 0; j < 4; j++) {
                        float rb = (float)ru[j], tb = (float)tu[j];
                        float d = rb - tb, d2 = d * d;
                        bool tz = (tb == 0.0f);
                        if (j & 1) {
                            ssb += (double)d2;
                            s0b += tz ? (double)d2 : 0.0;
                        } else {
                            ssa += (double)d2;
                            s0a += tz ? (double)d2 : 0.0;
                        }
                        c1 += tz ? 0 : 1;
                    }
                }
            }
        }
        double v3 = wred(s0a + s0b), v4 = wred(ssa + ssb), v5 = wred((double)c1);
        if (lane == 0) {
            atomicAdd(&accrow[6], v3);
            atomicAdd(&accrow[7], v4);
            atomicAdd(&accrow[8], v5);
        }
    }
}

__global__ void kfin(const double* __restrict__ acc, float* __restrict__ out,
                     int ncopy) {
    const int lane = threadIdx.x;  // 64 threads
    double v[9];
#pragma unroll
    for (int k = 0; k < 9; k++) v[k] = 0.0;
    if (lane < ncopy) {
#pragma unroll
        for (int k = 0; k < 9; k++) v[k] = acc[(size_t)lane * 16 + k];
    }
#pragma unroll
    for (int k = 0; k < 9; k++) {
#pragma unroll
        for (int o = 16; o > 0; o >>= 1) v[k] += __shfl_down(v[k], o, 64);
    }
    if (lane == 0) {
        const double NT = 8388608.0;   // 32*512*512
        const double NB = 16384000.0;  // 32*512*1000
        double vt_c1 = v[2], vy_c1 = v[5], vx_c1 = v[8];
        double vt_c0 = NT - vt_c1, vy_c0 = NB - vy_c1, vx_c0 = NB - vx_c1;
        double vt_s1 = v[1] - v[0];
        double vy_s1 = v[4] - v[3];
        double vx_s1 = v[7] - v[6];
        double vt = (vt_c0 > 0.0 ? v[0] / vt_c0 : 0.0) +
                    (vt_c1 > 0.0 ? vt_s1 / vt_c1 : 0.0);
        double vy = (vy_c0 > 0.0 ? v[3] / vy_c0 : 0.0) +
                    (vy_c1 > 0.0 ? vy_s1 / vy_c1 : 0.0);
        double vx = (vx_c0 > 0.0 ? v[6] / vx_c0 : 0.0) +
                    (vx_c1 > 0.0 ? vx_s1 / vx_c1 : 0.0);
        out[0] = (float)(vt + vx + vy);
    }
}

extern "C" void kernel_launch(void* const* d_in, const int* in_sizes, int n_in,
                              void* d_out, int out_size, void* d_ws, size_t ws_size,
                              hipStream_t stream) {
    const float* R = (const float*)d_in[0];  // reconstructed_image
    const float* T = (const float*)d_in[1];  // target_image
    double* acc = (double*)d_ws;
    float* out = (float*)d_out;

    int ncopy = 16;
    while (ncopy > 1 && (size_t)ncopy * 16 * sizeof(double) > ws_size) ncopy >>= 1;

    hipLaunchKernelGGL(kinit, dim3(1), dim3(256), 0, stream, acc, ncopy * 16);
    hipLaunchKernelGGL(kmain, dim3(2048), dim3(256), 0, stream, R, T, acc, ncopy - 1);
    hipLaunchKernelGGL(kfin, dim3(1), dim3(64), 0, stream, acc, out, ncopy);
}

// Round 4
// 86.428 us; speedup vs baseline: 1.0633x; 1.0633x over previous
//
#include <hip/hip_runtime.h>

#define TS 1000
// s_waitcnt immediate: lgkmcnt(0) ONLY (vmcnt=63 [3:0]+[15:14], expcnt=7 [6:4])
#define LGKM0 0xC07F

__device__ __forceinline__ double wred(double v) {
#pragma unroll
    for (int o = 32; o > 0; o >>= 1) v += __shfl_down(v, o, 64);
    return v;
}

__device__ __forceinline__ void scat(unsigned* bins, float v, unsigned val) {
    if (v != 0.0f) {
        int q = (int)(v * 1000.0f) - 1;
        if (q < 0) q += TS;
        atomicMax(&bins[q], val);
    }
}

__global__ void kinit(double* acc, int n) {
    int i = blockIdx.x * blockDim.x + threadIdx.x;
    if (i < n) acc[i] = 0.0;
}

// Even blocks: row transform (vy) + vt. Bins are WAVE-PRIVATE; the DS pipe
// processes one wave's LDS ops in order, so the row path needs NO block
// barriers: sched_barrier(0) pins compiler order, one lgkmcnt-only waitcnt
// (no vmcnt drain!) guards scatter->readback. Depth-1 prefetch of the next
// row's loads is therefore fully hidden.
// Odd blocks: column transform (vx); stripe in registers (round-2 scheme),
// 4 scatter phases with block barriers (bins shared across waves).
__global__ __launch_bounds__(256, 4) void kmain(const float* __restrict__ R,
                                                const float* __restrict__ T,
                                                double* __restrict__ acc,
                                                int ncopy_mask) {
    __shared__ unsigned bins[8000];
    const int tid = threadIdx.x;
    const int lane = tid & 63, wv = tid >> 6;
    const int id = blockIdx.x;
    const uint4 z4 = make_uint4(0u, 0u, 0u, 0u);
    double* accrow = acc + (size_t)(id & ncopy_mask) * 16;

    float s0 = 0.0f, ss = 0.0f;  // bin-MSE partials (f32; f64 at reduce)
    int c1 = 0;

    if ((id & 1) == 0) {
        // ============ rows: vt + vy (barrier-free, wave-private) ============
        const int kid = id >> 1;  // 0..1023, 16 rows per block, 4 per wave
        unsigned* bR = bins + wv * 2000;
        unsigned* bT = bR + 1000;
        uint4* r4 = (uint4*)bR;
        uint4* t4 = (uint4*)bT;
        // wave-private clear: 500 uint4 covers this wave's R+T slices
        for (int g = lane; g < 500; g += 64) r4[g] = z4;

        const float4* R4 = (const float4*)(R + (size_t)(kid * 16 + wv * 4) * 512);
        const float4* T4 = (const float4*)(T + (size_t)(kid * 16 + wv * 4) * 512);
        float t0 = 0.0f, tss = 0.0f;
        int tc1 = 0;

        float4 rv0 = R4[lane], rv1 = R4[lane + 64];
        float4 tv0 = T4[lane], tv1 = T4[lane + 64];
#pragma unroll
        for (int it = 0; it < 4; it++) {
            float4 nrv0 = rv0, nrv1 = rv1, ntv0 = tv0, ntv1 = tv1;
            if (it < 3) {  // prefetch next row; no barrier will drain vmcnt
                const int o = (it + 1) * 128;
                nrv0 = R4[o + lane];
                nrv1 = R4[o + lane + 64];
                ntv0 = T4[o + lane];
                ntv1 = T4[o + lane + 64];
            }
            __builtin_amdgcn_sched_barrier(0);  // clears/re-clears stay before scatter
            float rr[8] = {rv0.x, rv0.y, rv0.z, rv0.w, rv1.x, rv1.y, rv1.z, rv1.w};
            float tt[8] = {tv0.x, tv0.y, tv0.z, tv0.w, tv1.x, tv1.y, tv1.z, tv1.w};
#pragma unroll
            for (int j = 0; j < 8; j++) {
                float a = rr[j], b = tt[j];
                float d = a - b, d2 = d * d;
                bool bz = (b == 0.0f);
                tss += d2;
                t0 += bz ? d2 : 0.0f;
                tc1 += bz ? 0 : 1;
                const unsigned w = (unsigned)((j < 4 ? lane : lane + 64) * 4 + (j & 3));
                scat(bR, a, w);
                scat(bT, b, w);
            }
            __builtin_amdgcn_sched_barrier(0);
            __builtin_amdgcn_s_waitcnt(LGKM0);  // own-wave scatters drained
            __builtin_amdgcn_sched_barrier(0);
            for (int g = lane; g < 250; g += 64) {
                uint4 rg = r4[g], tg = t4[g];
                unsigned any = rg.x | rg.y | rg.z | rg.w | tg.x | tg.y | tg.z | tg.w;
                if (any) {
                    if (it < 3) { r4[g] = z4; t4[g] = z4; }
                    unsigned ru[4] = {rg.x, rg.y, rg.z, rg.w};
                    unsigned tu[4] = {tg.x, tg.y, tg.z, tg.w};
#pragma unroll
                    for (int j2 = 0; j2 < 4; j2++) {
                        float rb = (float)ru[j2], tb = (float)tu[j2];
                        float d = rb - tb, d2 = d * d;
                        bool tz = (tb == 0.0f);
                        ss += d2;
                        s0 += tz ? d2 : 0.0f;
                        c1 += tz ? 0 : 1;
                    }
                }
            }
            __builtin_amdgcn_sched_barrier(0);  // re-clears stay before next scatter
            rv0 = nrv0; rv1 = nrv1; tv0 = ntv0; tv1 = ntv1;
        }
        double v0 = wred((double)t0), v1 = wred((double)tss), v2 = wred((double)tc1);
        double v3 = wred((double)s0), v4 = wred((double)ss), v5 = wred((double)c1);
        if (lane == 0) {
            atomicAdd(&accrow[0], v0);
            atomicAdd(&accrow[1], v1);
            atomicAdd(&accrow[2], v2);
            atomicAdd(&accrow[3], v3);
            atomicAdd(&accrow[4], v4);
            atomicAdd(&accrow[5], v5);
        }
    } else {
        // ================= columns: vx =================
        const int kid = id >> 1;    // 0..1023
        const int b = kid >> 5;     // image
        const int line = kid & 31;  // 16-column stripe
        const float* Rb = R + (size_t)b * (512 * 512) + (size_t)line * 16;
        const float* Tb = T + (size_t)b * (512 * 512) + (size_t)line * 16;

        // block-wide clear
        {
            uint4* p = (uint4*)bins;
            for (int i = tid; i < 2000; i += 256) p[i] = z4;
        }

        // Load whole stripe once: 4-lane group g=tid>>2 covers one row's 64B;
        // quad ownership rotates (sub=(tid+k)&3) so each phase has 2 matching
        // register quads per thread.
        float4 ra[8], ta[8];
#pragma unroll
        for (int k = 0; k < 8; k++) {
            const int h = k * 64 + (tid >> 2);
            const int sub = (tid + k) & 3;
            const size_t off = (size_t)h * 512 + sub * 4;
            ra[k] = *(const float4*)(Rb + off);
            ta[k] = *(const float4*)(Tb + off);
        }
        __syncthreads();  // clear visible to all waves

        uint4* r4 = (uint4*)bins;           // [4 cols][1000] for R
        uint4* t4 = (uint4*)(bins + 4000);  // [4 cols][1000] for T
#pragma unroll
        for (int p = 0; p < 4; p++) {
#pragma unroll
            for (int k = 0; k < 8; k++) {
                if (((tid + k) & 3) == p) {
                    const unsigned h = (unsigned)(k * 64 + (tid >> 2));
                    scat(bins + 0 * 1000, ra[k].x, h);
                    scat(bins + 1 * 1000, ra[k].y, h);
                    scat(bins + 2 * 1000, ra[k].z, h);
                    scat(bins + 3 * 1000, ra[k].w, h);
                    scat(bins + 4000 + 0 * 1000, ta[k].x, h);
                    scat(bins + 4000 + 1 * 1000, ta[k].y, h);
                    scat(bins + 4000 + 2 * 1000, ta[k].z, h);
                    scat(bins + 4000 + 3 * 1000, ta[k].w, h);
                }
            }
            __syncthreads();  // scatters visible to all waves
            for (int g = tid; g < 1000; g += 256) {
                uint4 rg = r4[g], tg = t4[g];
                unsigned any = rg.x | rg.y | rg.z | rg.w | tg.x | tg.y | tg.z | tg.w;
                if (any) {
                    if (p < 3) { r4[g] = z4; t4[g] = z4; }
                    unsigned ru[4] = {rg.x, rg.y, rg.z, rg.w};
                    unsigned tu[4] = {tg.x, tg.y, tg.z, tg.w};
#pragma unroll
                    for (int j = 0; j < 4; j++) {
                        float rb = (float)ru[j], tb = (float)tu[j];
                        float d = rb - tb, d2 = d * d;
                        bool tz = (tb == 0.0f);
                        ss += d2;
                        s0 += tz ? d2 : 0.0f;
                        c1 += tz ? 0 : 1;
                    }
                }
            }
            if (p < 3) __syncthreads();  // re-clears visible before next scatter
        }
        double v3 = wred((double)s0), v4 = wred((double)ss), v5 = wred((double)c1);
        if (lane == 0) {
            atomicAdd(&accrow[6], v3);
            atomicAdd(&accrow[7], v4);
            atomicAdd(&accrow[8], v5);
        }
    }
}

__global__ void kfin(const double* __restrict__ acc, float* __restrict__ out,
                     int ncopy) {
    const int lane = threadIdx.x;  // 64 threads
    double v[9];
#pragma unroll
    for (int k = 0; k < 9; k++) v[k] = 0.0;
    if (lane < ncopy) {
#pragma unroll
        for (int k = 0; k < 9; k++) v[k] = acc[(size_t)lane * 16 + k];
    }
#pragma unroll
    for (int k = 0; k < 9; k++) {
#pragma unroll
        for (int o = 16; o > 0; o >>= 1) v[k] += __shfl_down(v[k], o, 64);
    }
    if (lane == 0) {
        const double NT = 8388608.0;   // 32*512*512
        const double NB = 16384000.0;  // 32*512*1000
        double vt_c1 = v[2], vy_c1 = v[5], vx_c1 = v[8];
        double vt_c0 = NT - vt_c1, vy_c0 = NB - vy_c1, vx_c0 = NB - vx_c1;
        double vt_s1 = v[1] - v[0];
        double vy_s1 = v[4] - v[3];
        double vx_s1 = v[7] - v[6];
        double vt = (vt_c0 > 0.0 ? v[0] / vt_c0 : 0.0) +
                    (vt_c1 > 0.0 ? vt_s1 / vt_c1 : 0.0);
        double vy = (vy_c0 > 0.0 ? v[3] / vy_c0 : 0.0) +
                    (vy_c1 > 0.0 ? vy_s1 / vy_c1 : 0.0);
        double vx = (vx_c0 > 0.0 ? v[6] / vx_c0 : 0.0) +
                    (vx_c1 > 0.0 ? vx_s1 / vx_c1 : 0.0);
        out[0] = (float)(vt + vx + vy);
    }
}

extern "C" void kernel_launch(void* const* d_in, const int* in_sizes, int n_in,
                              void* d_out, int out_size, void* d_ws, size_t ws_size,
                              hipStream_t stream) {
    const float* R = (const float*)d_in[0];  // reconstructed_image
    const float* T = (const float*)d_in[1];  // target_image
    double* acc = (double*)d_ws;
    float* out = (float*)d_out;

    int ncopy = 16;
    while (ncopy > 1 && (size_t)ncopy * 16 * sizeof(double) > ws_size) ncopy >>= 1;

    hipLaunchKernelGGL(kinit, dim3(1), dim3(256), 0, stream, acc, ncopy * 16);
    hipLaunchKernelGGL(kmain, dim3(2048), dim3(256), 0, stream, R, T, acc, ncopy - 1);
    hipLaunchKernelGGL(kfin, dim3(1), dim3(64), 0, stream, acc, out, ncopy);
}